// Round 1
// baseline (2016.655 us; speedup 1.0000x reference)
//
#include <hip/hip_runtime.h>
#include <math.h>

// Problem constants (fixed shapes)
//  B=4, N=2048, D_MODEL=1024, N_HEADS=16, KV_HEADS=4, G=4, D_HEAD=64
//  NUM_BUCKETS=32, MAX_DISTANCE=128

// ---------------------------------------------------------------------------
// Kernel 1: reduce weights over the group axis + precompute bias table.
//  Wq_e[h*64+d, k] = sum_g Wq[(g*4+h)*64+d, k]              [256,1024]
//  Wk_e, Wv_e      = 0.25 * sum_g (mean)                    [256,1024]
//  Wo_e[m, c]      = sum_g Wo[m, g*256+c]                   [1024,256]
//  btab[h][delta+2048] = mean_g rel_bias[bucket(delta), g*4+h]   [4,4096]
// ---------------------------------------------------------------------------
__global__ void reduce_weights(const float* __restrict__ Wq, const float* __restrict__ Wk,
                               const float* __restrict__ Wv, const float* __restrict__ Wo,
                               const float* __restrict__ rb,
                               float* __restrict__ Wq_e, float* __restrict__ Wk_e,
                               float* __restrict__ Wv_e, float* __restrict__ Wo_e,
                               float* __restrict__ btab) {
    int idx = blockIdx.x * 256 + threadIdx.x;
    if (idx < 256 * 1024) {
        int row = idx >> 10;      // h*64+d
        int col = idx & 1023;
        int h = row >> 6, d = row & 63;
        float sq = 0.f, sk = 0.f, sv = 0.f;
        #pragma unroll
        for (int g = 0; g < 4; ++g) {
            int src = ((g * 4 + h) * 64 + d) * 1024 + col;
            sq += Wq[src]; sk += Wk[src]; sv += Wv[src];
        }
        Wq_e[idx] = sq;             // einsum sums over g for q
        Wk_e[idx] = sk * 0.25f;     // mean over g
        Wv_e[idx] = sv * 0.25f;
    }
    if (idx < 1024 * 256) {
        int m = idx >> 8; int c = idx & 255;
        float s = 0.f;
        #pragma unroll
        for (int g = 0; g < 4; ++g) s += Wo[m * 1024 + g * 256 + c];
        Wo_e[idx] = s;              // tile(out,G) @ Wo.T == out @ Wo_e.T
    }
    if (idx < 4 * 4096) {
        int h = idx >> 12; int dpos = idx & 4095;
        int delta = dpos - 2048;    // key - query (memory - context)
        int bucket = (delta > 0) ? 16 : 0;
        int ad = delta < 0 ? -delta : delta;
        if (ad < 8) {
            bucket += ad;
        } else {
            float rp = (float)ad;
            int large = 8 + (int)(logf(rp * 0.125f) / logf(16.0f) * 8.0f);
            bucket += (large < 15) ? large : 15;
        }
        float s = 0.f;
        #pragma unroll
        for (int g = 0; g < 4; ++g) s += rb[bucket * 16 + g * 4 + h];
        btab[idx] = s * 0.25f;      // mean over g
    }
}

// ---------------------------------------------------------------------------
// Kernel 2: generic NT GEMM, C[M,N] = A[M,K] * B[N,K]^T  (all row-major).
// 16x16 LDS tile, one output per thread. Correctness-first.
// ---------------------------------------------------------------------------
__global__ __launch_bounds__(256) void gemm_nt(const float* __restrict__ A,
                                               const float* __restrict__ B,
                                               float* __restrict__ C,
                                               int M, int N, int K) {
    __shared__ float As[16][17];
    __shared__ float Bs[16][17];
    int tx = threadIdx.x, ty = threadIdx.y;
    int row = blockIdx.y * 16 + ty;
    int colBase = blockIdx.x * 16;
    float acc = 0.f;
    for (int k0 = 0; k0 < K; k0 += 16) {
        As[ty][tx] = A[(size_t)row * K + k0 + tx];
        Bs[ty][tx] = B[(size_t)(colBase + ty) * K + k0 + tx];
        __syncthreads();
        #pragma unroll
        for (int kk = 0; kk < 16; ++kk) acc += As[ty][kk] * Bs[tx][kk];
        __syncthreads();
    }
    C[(size_t)row * N + colBase + tx] = acc;
}

// ---------------------------------------------------------------------------
// Kernel 3: flash-style attention with online softmax.
//  q,k,v: [B*2048, 256] with kv-head h occupying cols [h*64, h*64+64)
//  One block = one (b, h, 32-row q-tile). 256 threads: thread t handles
//  q-row r = t/8; for scores it owns 8 keys (lane8*8..+8), for the PV
//  accumulate it owns 8 output dims (lane8*8..+8). Row state (m,l) lives in
//  LDS, touched only by the row's 8 threads (same wave -> ordered, no race).
//  LDS stride 65 (odd) -> conflict-free for all access patterns used here.
// ---------------------------------------------------------------------------
#define TQ 32
#define TK 64
#define SPAD 65

__global__ __launch_bounds__(256) void flash_attn(const float* __restrict__ q,
                                                  const float* __restrict__ k,
                                                  const float* __restrict__ v,
                                                  const float* __restrict__ btab,
                                                  float* __restrict__ o) {
    __shared__ float qs[TQ * SPAD];
    __shared__ float ks[TK * SPAD];
    __shared__ float vs[TK * SPAD];
    __shared__ float ps[TQ * SPAD];
    __shared__ float m_s[TQ], l_s[TQ];

    int tid = threadIdx.x;
    int b = blockIdx.z, h = blockIdx.y;
    int q0 = blockIdx.x * TQ;
    int r = tid >> 3;       // q-row within tile, 0..31
    int lane8 = tid & 7;    // 0..7

    for (int i = tid; i < TQ * 64; i += 256) {
        int row = i >> 6, col = i & 63;
        qs[row * SPAD + col] = q[(size_t)(b * 2048 + q0 + row) * 256 + h * 64 + col];
    }
    if (tid < TQ) { m_s[tid] = -3.0e38f; l_s[tid] = 0.f; }
    float acc[8];
    #pragma unroll
    for (int d = 0; d < 8; ++d) acc[d] = 0.f;
    __syncthreads();

    const float* bt = btab + h * 4096 + 2048 - (q0 + r);

    for (int kt = 0; kt < 2048; kt += TK) {
        for (int i = tid; i < TK * 64; i += 256) {
            int row = i >> 6, col = i & 63;
            size_t gidx = (size_t)(b * 2048 + kt + row) * 256 + h * 64 + col;
            ks[row * SPAD + col] = k[gidx];
            vs[row * SPAD + col] = v[gidx];
        }
        __syncthreads();

        // scores for 8 keys
        float s[8];
        float lmax = -3.0e38f;
        #pragma unroll
        for (int jj = 0; jj < 8; ++jj) {
            int j = lane8 * 8 + jj;
            float dot = 0.f;
            #pragma unroll
            for (int kk = 0; kk < 64; ++kk) dot += qs[r * SPAD + kk] * ks[j * SPAD + kk];
            dot += bt[kt + j];
            s[jj] = dot;
            lmax = fmaxf(lmax, dot);
        }
        #pragma unroll
        for (int off = 4; off >= 1; off >>= 1) lmax = fmaxf(lmax, __shfl_xor(lmax, off, 8));

        float mold = m_s[r];
        float mnew = fmaxf(mold, lmax);
        float lsum = 0.f;
        #pragma unroll
        for (int jj = 0; jj < 8; ++jj) {
            float p = expf(s[jj] - mnew);
            ps[r * SPAD + lane8 * 8 + jj] = p;
            lsum += p;
        }
        #pragma unroll
        for (int off = 4; off >= 1; off >>= 1) lsum += __shfl_xor(lsum, off, 8);

        float alpha = expf(mold - mnew);
        if (lane8 == 0) { m_s[r] = mnew; l_s[r] = alpha * l_s[r] + lsum; }

        #pragma unroll
        for (int d = 0; d < 8; ++d) acc[d] *= alpha;
        for (int key = 0; key < TK; ++key) {
            float p = ps[r * SPAD + key];
            #pragma unroll
            for (int d = 0; d < 8; ++d) acc[d] += p * vs[key * SPAD + lane8 * 8 + d];
        }
        __syncthreads();
    }

    float inv = 1.0f / l_s[r];
    #pragma unroll
    for (int d = 0; d < 8; ++d)
        o[(size_t)(b * 2048 + q0 + r) * 256 + h * 64 + lane8 * 8 + d] = acc[d] * inv;
}

// ---------------------------------------------------------------------------
// Launch. Workspace layout (floats):
//  Wq_e 256K | Wk_e 256K | Wv_e 256K | Wo_e 256K | btab 16K |
//  q 2M | k 2M | v 2M | attn 2M    -> ~9.45M floats = 37.8 MB
// ---------------------------------------------------------------------------
extern "C" void kernel_launch(void* const* d_in, const int* in_sizes, int n_in,
                              void* d_out, int out_size, void* d_ws, size_t ws_size,
                              hipStream_t stream) {
    (void)in_sizes; (void)n_in; (void)out_size; (void)ws_size;
    const float* hs = (const float*)d_in[0];
    const float* Wq = (const float*)d_in[1];
    const float* Wk = (const float*)d_in[2];
    const float* Wv = (const float*)d_in[3];
    const float* Wo = (const float*)d_in[4];
    const float* rb = (const float*)d_in[5];
    float* ws = (float*)d_ws;

    float* Wq_e = ws;
    float* Wk_e = Wq_e + 256 * 1024;
    float* Wv_e = Wk_e + 256 * 1024;
    float* Wo_e = Wv_e + 256 * 1024;
    float* btab = Wo_e + 1024 * 256;
    float* qb   = btab + 4 * 4096;
    float* kb   = qb + 8192 * 256;
    float* vb   = kb + 8192 * 256;
    float* ab   = vb + 8192 * 256;
    float* out  = (float*)d_out;

    reduce_weights<<<1024, 256, 0, stream>>>(Wq, Wk, Wv, Wo, rb, Wq_e, Wk_e, Wv_e, Wo_e, btab);

    dim3 blk(16, 16);
    gemm_nt<<<dim3(16, 512), blk, 0, stream>>>(hs, Wq_e, qb, 8192, 256, 1024);
    gemm_nt<<<dim3(16, 512), blk, 0, stream>>>(hs, Wk_e, kb, 8192, 256, 1024);
    gemm_nt<<<dim3(16, 512), blk, 0, stream>>>(hs, Wv_e, vb, 8192, 256, 1024);

    flash_attn<<<dim3(64, 4, 4), 256, 0, stream>>>(qb, kb, vb, btab, ab);

    gemm_nt<<<dim3(64, 512), blk, 0, stream>>>(ab, Wo_e, out, 8192, 1024, 256);
}

// Round 4
// 258.139 us; speedup vs baseline: 7.8123x; 7.8123x over previous
//
#include <hip/hip_runtime.h>
#include <math.h>

typedef _Float16 half_t;
typedef _Float16 half8 __attribute__((ext_vector_type(8)));
typedef float f32x4 __attribute__((ext_vector_type(4)));

#define LOG2E 1.44269504088896f

// ---------------------------------------------------------------------------
// prep: effective weights (group-reduced) in fp16 + bias table fp32.
//  Wqkv rows 0..255 q (sum over g), 256..511 k (mean), 512..767 v (mean)
//  Wo_e[m, c] = sum_g Wo[m, g*256+c]                       [1024,256]
//  btab[h][delta+2048] = mean_g rel_bias[bucket(delta), g*4+h]   [4,4096]
// ---------------------------------------------------------------------------
__global__ void prep(const float* __restrict__ Wq, const float* __restrict__ Wk,
                     const float* __restrict__ Wv, const float* __restrict__ Wo,
                     const float* __restrict__ rb,
                     half_t* __restrict__ Wqkv, half_t* __restrict__ Wo_e,
                     float* __restrict__ btab) {
    int idx = blockIdx.x * 256 + threadIdx.x;
    if (idx < 768 * 1024) {
        int row = idx >> 10, col = idx & 1023;
        int sec = row >> 8;            // 0=q, 1=k, 2=v
        int r = row & 255;
        int h = r >> 6, d = r & 63;
        const float* W = (sec == 0) ? Wq : ((sec == 1) ? Wk : Wv);
        float s = 0.f;
        #pragma unroll
        for (int g = 0; g < 4; ++g) s += W[((g * 4 + h) * 64 + d) * 1024 + col];
        if (sec != 0) s *= 0.25f;
        Wqkv[idx] = (half_t)s;
    }
    if (idx < 1024 * 256) {
        int m = idx >> 8, c = idx & 255;
        float s = 0.f;
        #pragma unroll
        for (int g = 0; g < 4; ++g) s += Wo[m * 1024 + g * 256 + c];
        Wo_e[idx] = (half_t)s;
    }
    if (idx < 4 * 4096) {
        int h = idx >> 12, dpos = idx & 4095;
        int delta = dpos - 2048;
        int bucket = (delta > 0) ? 16 : 0;
        int ad = delta < 0 ? -delta : delta;
        if (ad < 8) bucket += ad;
        else {
            int large = 8 + (int)(logf((float)ad * 0.125f) / logf(16.0f) * 8.0f);
            bucket += (large < 15) ? large : 15;
        }
        float s = 0.f;
        #pragma unroll
        for (int g = 0; g < 4; ++g) s += rb[bucket * 16 + g * 4 + h];
        btab[idx] = s * 0.25f;
    }
}

// ---------------------------------------------------------------------------
// MFMA NT GEMM: C[M,N] = A[M,K] * B[N,K]^T.  A fp32 or fp16, B fp16,
// C fp16 or fp32.  128x128 block tile, 4 waves (2x2) of 64x64, BK=32.
// LDS stride 40 halfs (80 B): 16B-aligned b128 frag reads.
// ---------------------------------------------------------------------------
__global__ __launch_bounds__(256) void gemm_nt_mfma(const void* __restrict__ Aptr,
                                                    const half_t* __restrict__ B,
                                                    void* __restrict__ Cptr,
                                                    int M, int N, int K,
                                                    int a_fp32, int store_half) {
    __shared__ __attribute__((aligned(16))) half_t As[128 * 40];
    __shared__ __attribute__((aligned(16))) half_t Bs[128 * 40];
    int tid = threadIdx.x;
    int w = tid >> 6, lane = tid & 63;
    int c = lane & 15, quad = lane >> 4;
    int rowBase = blockIdx.y * 128, colBase = blockIdx.x * 128;
    int wr = (w & 1) * 64, wc = (w >> 1) * 64;

    f32x4 acc[4][4];
    #pragma unroll
    for (int i = 0; i < 4; ++i)
        #pragma unroll
        for (int j = 0; j < 4; ++j) acc[i][j] = (f32x4)(0.f);

    int r = tid >> 2;              // 0..63
    int kc = (tid & 3) * 8;        // 0,8,16,24

    for (int k0 = 0; k0 < K; k0 += 32) {
        __syncthreads();
        #pragma unroll
        for (int p = 0; p < 2; ++p) {
            int row = r + p * 64;
            if (a_fp32) {
                const float* A = (const float*)Aptr;
                const f32x4* src = (const f32x4*)&A[(size_t)(rowBase + row) * K + k0 + kc];
                f32x4 f0 = src[0], f1 = src[1];
                half8 hh;
                #pragma unroll
                for (int j = 0; j < 4; ++j) { hh[j] = (half_t)f0[j]; hh[j + 4] = (half_t)f1[j]; }
                *(half8*)&As[row * 40 + kc] = hh;
            } else {
                const half_t* A = (const half_t*)Aptr;
                *(half8*)&As[row * 40 + kc] =
                    *(const half8*)&A[(size_t)(rowBase + row) * K + k0 + kc];
            }
            *(half8*)&Bs[row * 40 + kc] =
                *(const half8*)&B[(size_t)(colBase + row) * K + k0 + kc];
        }
        __syncthreads();

        half8 af[4], bfr[4];
        #pragma unroll
        for (int i = 0; i < 4; ++i)
            af[i] = *(const half8*)&As[(wr + i * 16 + c) * 40 + quad * 8];
        #pragma unroll
        for (int j = 0; j < 4; ++j)
            bfr[j] = *(const half8*)&Bs[(wc + j * 16 + c) * 40 + quad * 8];
        #pragma unroll
        for (int i = 0; i < 4; ++i)
            #pragma unroll
            for (int j = 0; j < 4; ++j)
                acc[i][j] = __builtin_amdgcn_mfma_f32_16x16x32_f16(af[i], bfr[j], acc[i][j], 0, 0, 0);
    }

    #pragma unroll
    for (int i = 0; i < 4; ++i)
        #pragma unroll
        for (int j = 0; j < 4; ++j)
            #pragma unroll
            for (int reg = 0; reg < 4; ++reg) {
                size_t row = rowBase + wr + i * 16 + quad * 4 + reg;
                size_t col = colBase + wc + j * 16 + c;
                if (store_half) ((half_t*)Cptr)[row * N + col] = (half_t)acc[i][j][reg];
                else            ((float*)Cptr)[row * N + col] = acc[i][j][reg];
            }
}

// ---------------------------------------------------------------------------
// transpose V: vt[(b*4+h)*64 + d][n] = qkv[b*2048+n][512 + h*64 + d]
// ---------------------------------------------------------------------------
__global__ __launch_bounds__(256) void transpose_v(const half_t* __restrict__ qkv,
                                                   half_t* __restrict__ vt) {
    __shared__ __attribute__((aligned(16))) half_t T[64 * 65];
    int tid = threadIdx.x;
    int bh = blockIdx.y;            // b*4+h
    int b = bh >> 2, h = bh & 3;
    int n0 = blockIdx.x * 64;

    int n = tid >> 2;               // 0..63
    int dc = (tid & 3) * 16;        // 0,16,32,48
    const half_t* src = qkv + (size_t)(b * 2048 + n0 + n) * 768 + 512 + h * 64 + dc;
    half8 v0 = *(const half8*)(src);
    half8 v1 = *(const half8*)(src + 8);
    #pragma unroll
    for (int j = 0; j < 8; ++j) {
        T[(dc + j) * 65 + n] = v0[j];
        T[(dc + 8 + j) * 65 + n] = v1[j];
    }
    __syncthreads();

    int d = tid >> 2;               // 0..63
    int nc = (tid & 3) * 16;
    half8 o0, o1;
    #pragma unroll
    for (int j = 0; j < 8; ++j) {
        o0[j] = T[d * 65 + nc + j];
        o1[j] = T[d * 65 + nc + 8 + j];
    }
    half_t* dst = vt + (size_t)(bh * 64 + d) * 2048 + n0 + nc;
    *(half8*)(dst) = o0;
    *(half8*)(dst + 8) = o1;
}

// ---------------------------------------------------------------------------
// MFMA flash attention (fp16 in, fp32 accum). Block = one (b,h) x 64 q-rows;
// 4 waves x 16 rows. S = Q K^T (MFMA), online softmax in regs (quad-local
// shfl), P via LDS round-trip (sync-hardened), O += P V (MFMA, V^T staged).
// ---------------------------------------------------------------------------
__global__ __launch_bounds__(256) void attn(const half_t* __restrict__ qkv,
                                            const half_t* __restrict__ vt,
                                            const float* __restrict__ btab,
                                            half_t* __restrict__ ab) {
    __shared__ __attribute__((aligned(16))) half_t Qs[64 * 72];
    __shared__ __attribute__((aligned(16))) half_t Ks[64 * 72];
    __shared__ __attribute__((aligned(16))) half_t Vts[64 * 72];
    __shared__ __attribute__((aligned(16))) half_t Ps[4 * 16 * 72];
    __shared__ float bwin[128];

    int tid = threadIdx.x;
    int w = tid >> 6, lane = tid & 63;
    int c = lane & 15, quad = lane >> 4;
    int b = blockIdx.z, h = blockIdx.y;
    int q0 = blockIdx.x * 64;

    {
        int r = tid >> 2;
        int dc = (tid & 3) * 16;
        const half_t* src = qkv + (size_t)(b * 2048 + q0 + r) * 768 + h * 64 + dc;
        *(half8*)&Qs[r * 72 + dc] = *(const half8*)(src);
        *(half8*)&Qs[r * 72 + dc + 8] = *(const half8*)(src + 8);
    }
    __syncthreads();
    half8 qf0 = *(const half8*)&Qs[(w * 16 + c) * 72 + quad * 8];
    half8 qf1 = *(const half8*)&Qs[(w * 16 + c) * 72 + 32 + quad * 8];

    f32x4 O[4];
    #pragma unroll
    for (int i = 0; i < 4; ++i) O[i] = (f32x4)(0.f);
    float mrow[4], lrow[4];
    #pragma unroll
    for (int rg = 0; rg < 4; ++rg) { mrow[rg] = -1e30f; lrow[rg] = 0.f; }

    for (int kt = 0; kt < 2048; kt += 64) {
        __syncthreads();
        {
            int r = tid >> 2;
            int dc = (tid & 3) * 16;
            const half_t* ksrc = qkv + (size_t)(b * 2048 + kt + r) * 768 + 256 + h * 64 + dc;
            *(half8*)&Ks[r * 72 + dc] = *(const half8*)(ksrc);
            *(half8*)&Ks[r * 72 + dc + 8] = *(const half8*)(ksrc + 8);
            const half_t* vsrc = vt + (size_t)((b * 4 + h) * 64 + r) * 2048 + kt + dc;
            *(half8*)&Vts[r * 72 + dc] = *(const half8*)(vsrc);
            *(half8*)&Vts[r * 72 + dc + 8] = *(const half8*)(vsrc + 8);
            if (tid < 128) {
                int widx = 2048 + kt - q0 - 63 + tid;
                widx = widx < 0 ? 0 : (widx > 4095 ? 4095 : widx);
                bwin[tid] = btab[h * 4096 + widx];
            }
        }
        __syncthreads();

        // S = Q K^T : 16 q-rows x 64 keys per wave
        f32x4 S[4];
        #pragma unroll
        for (int kb = 0; kb < 4; ++kb) {
            half8 b0 = *(const half8*)&Ks[(kb * 16 + c) * 72 + quad * 8];
            half8 b1 = *(const half8*)&Ks[(kb * 16 + c) * 72 + 32 + quad * 8];
            f32x4 a = (f32x4)(0.f);
            a = __builtin_amdgcn_mfma_f32_16x16x32_f16(qf0, b0, a, 0, 0, 0);
            a = __builtin_amdgcn_mfma_f32_16x16x32_f16(qf1, b1, a, 0, 0, 0);
            S[kb] = a;
        }

        float mnew[4];
        #pragma unroll
        for (int rg = 0; rg < 4; ++rg) mnew[rg] = mrow[rg];
        #pragma unroll
        for (int kb = 0; kb < 4; ++kb)
            #pragma unroll
            for (int rg = 0; rg < 4; ++rg) {
                int bi = 63 + (kb * 16 + c) - (w * 16 + quad * 4 + rg);
                float s = (S[kb][rg] + bwin[bi]) * LOG2E;
                S[kb][rg] = s;
                mnew[rg] = fmaxf(mnew[rg], s);
            }
        #pragma unroll
        for (int off = 1; off < 16; off <<= 1)
            #pragma unroll
            for (int rg = 0; rg < 4; ++rg)
                mnew[rg] = fmaxf(mnew[rg], __shfl_xor(mnew[rg], off));

        float alpha[4];
        #pragma unroll
        for (int rg = 0; rg < 4; ++rg) {
            alpha[rg] = exp2f(mrow[rg] - mnew[rg]);
            mrow[rg] = mnew[rg];
        }
        float lsum[4] = {0.f, 0.f, 0.f, 0.f};
        #pragma unroll
        for (int kb = 0; kb < 4; ++kb)
            #pragma unroll
            for (int rg = 0; rg < 4; ++rg) {
                float p = exp2f(S[kb][rg] - mrow[rg]);
                S[kb][rg] = p;
                lsum[rg] += p;
            }
        #pragma unroll
        for (int off = 1; off < 16; off <<= 1)
            #pragma unroll
            for (int rg = 0; rg < 4; ++rg)
                lsum[rg] += __shfl_xor(lsum[rg], off);
        #pragma unroll
        for (int rg = 0; rg < 4; ++rg) lrow[rg] = lrow[rg] * alpha[rg] + lsum[rg];

        // P: C-layout -> LDS matrix -> A-layout (sync-hardened round trip)
        half_t* pw = &Ps[w * 16 * 72];
        #pragma unroll
        for (int kb = 0; kb < 4; ++kb)
            #pragma unroll
            for (int rg = 0; rg < 4; ++rg)
                pw[(quad * 4 + rg) * 72 + kb * 16 + c] = (half_t)S[kb][rg];
        __syncthreads();

        half8 pf0 = *(const half8*)&pw[c * 72 + quad * 8];
        half8 pf1 = *(const half8*)&pw[c * 72 + 32 + quad * 8];
        #pragma unroll
        for (int db = 0; db < 4; ++db) {
            f32x4 o = O[db];
            #pragma unroll
            for (int rg = 0; rg < 4; ++rg) o[rg] *= alpha[rg];
            half8 v0 = *(const half8*)&Vts[(db * 16 + c) * 72 + quad * 8];
            half8 v1 = *(const half8*)&Vts[(db * 16 + c) * 72 + 32 + quad * 8];
            o = __builtin_amdgcn_mfma_f32_16x16x32_f16(pf0, v0, o, 0, 0, 0);
            o = __builtin_amdgcn_mfma_f32_16x16x32_f16(pf1, v1, o, 0, 0, 0);
            O[db] = o;
        }
    }

    // epilogue: NOTE the + h*64 — this was the round-2/3 bug.
    #pragma unroll
    for (int db = 0; db < 4; ++db)
        #pragma unroll
        for (int rg = 0; rg < 4; ++rg) {
            float val = O[db][rg] / lrow[rg];
            ab[(size_t)(b * 2048 + q0 + w * 16 + quad * 4 + rg) * 256
               + h * 64 + db * 16 + c] = (half_t)val;
        }
}

// ---------------------------------------------------------------------------
// Launch. ws layout: Wqkv 1.5M | Wo_e .5M | btab 64K | qkv 12M | vt 4M | ab 4M
// ---------------------------------------------------------------------------
extern "C" void kernel_launch(void* const* d_in, const int* in_sizes, int n_in,
                              void* d_out, int out_size, void* d_ws, size_t ws_size,
                              hipStream_t stream) {
    (void)in_sizes; (void)n_in; (void)out_size; (void)ws_size;
    const float* hs = (const float*)d_in[0];
    const float* Wq = (const float*)d_in[1];
    const float* Wk = (const float*)d_in[2];
    const float* Wv = (const float*)d_in[3];
    const float* Wo = (const float*)d_in[4];
    const float* rb = (const float*)d_in[5];

    char* p = (char*)d_ws;
    half_t* Wqkv = (half_t*)p;            p += 768 * 1024 * 2;
    half_t* Wo_e = (half_t*)p;            p += 1024 * 256 * 2;
    float*  btab = (float*)p;             p += 4 * 4096 * 4;
    half_t* qkv  = (half_t*)p;            p += (size_t)8192 * 768 * 2;
    half_t* vt   = (half_t*)p;            p += (size_t)16 * 64 * 2048 * 2;
    half_t* ab   = (half_t*)p;            p += (size_t)8192 * 256 * 2;
    float*  out  = (float*)d_out;

    prep<<<3072, 256, 0, stream>>>(Wq, Wk, Wv, Wo, rb, Wqkv, Wo_e, btab);

    // fused QKV projection: qkv[8192,768] = hs[8192,1024] * Wqkv[768,1024]^T
    gemm_nt_mfma<<<dim3(6, 64), 256, 0, stream>>>(hs, Wqkv, qkv, 8192, 768, 1024, 1, 1);

    transpose_v<<<dim3(32, 16), 256, 0, stream>>>(qkv, vt);

    attn<<<dim3(32, 4, 4), 256, 0, stream>>>(qkv, vt, btab, ab);

    // out[8192,1024] = ab[8192,256] * Wo_e[1024,256]^T
    gemm_nt_mfma<<<dim3(8, 64), 256, 0, stream>>>(ab, Wo_e, out, 8192, 1024, 256, 0, 0);
}

// Round 5
// 226.223 us; speedup vs baseline: 8.9144x; 1.1411x over previous
//
#include <hip/hip_runtime.h>
#include <math.h>

typedef _Float16 half_t;
typedef _Float16 half8 __attribute__((ext_vector_type(8)));
typedef float f32x4 __attribute__((ext_vector_type(4)));

#define LOG2E 1.44269504088896f

// async global -> LDS, 16 B per lane. lds ptr must be wave-uniform base;
// HW writes lane i at base + i*16.
__device__ __forceinline__ void gload16(const void* g, void* l) {
    __builtin_amdgcn_global_load_lds(
        (const __attribute__((address_space(1))) unsigned int*)g,
        (__attribute__((address_space(3))) unsigned int*)l, 16, 0, 0);
}

// ---------------------------------------------------------------------------
// prep: group-reduced effective weights (fp16) + bias table (fp32).
//  Wqkv rows 0..255 q (sum over g, x LOG2E), 256..511 k (mean), 512..767 v (mean)
//  Wo_e[m,c] = sum_g Wo[m, g*256+c]
//  btab[h][delta+2048] = LOG2E * mean_g rel_bias[bucket(delta), g*4+h]
// ---------------------------------------------------------------------------
__global__ void prep(const float* __restrict__ Wq, const float* __restrict__ Wk,
                     const float* __restrict__ Wv, const float* __restrict__ Wo,
                     const float* __restrict__ rb,
                     half_t* __restrict__ Wqkv, half_t* __restrict__ Wo_e,
                     float* __restrict__ btab) {
    int idx = blockIdx.x * 256 + threadIdx.x;
    if (idx < 768 * 1024) {
        int row = idx >> 10, col = idx & 1023;
        int sec = row >> 8;
        int r = row & 255;
        int h = r >> 6, d = r & 63;
        const float* W = (sec == 0) ? Wq : ((sec == 1) ? Wk : Wv);
        float s = 0.f;
        #pragma unroll
        for (int g = 0; g < 4; ++g) s += W[((g * 4 + h) * 64 + d) * 1024 + col];
        s *= (sec == 0) ? LOG2E : 0.25f;   // fold log2e into q-projection
        Wqkv[idx] = (half_t)s;
    }
    if (idx < 1024 * 256) {
        int m = idx >> 8, c = idx & 255;
        float s = 0.f;
        #pragma unroll
        for (int g = 0; g < 4; ++g) s += Wo[m * 1024 + g * 256 + c];
        Wo_e[idx] = (half_t)s;
    }
    if (idx < 4 * 4096) {
        int h = idx >> 12, dpos = idx & 4095;
        int delta = dpos - 2048;
        int bucket = (delta > 0) ? 16 : 0;
        int ad = delta < 0 ? -delta : delta;
        if (ad < 8) bucket += ad;
        else {
            int large = 8 + (int)(logf((float)ad * 0.125f) / logf(16.0f) * 8.0f);
            bucket += (large < 15) ? large : 15;
        }
        float s = 0.f;
        #pragma unroll
        for (int g = 0; g < 4; ++g) s += rb[bucket * 16 + g * 4 + h];
        btab[idx] = s * 0.25f * LOG2E;     // log2-domain bias
    }
}

// ---------------------------------------------------------------------------
// hs fp32 -> fp16
// ---------------------------------------------------------------------------
__global__ __launch_bounds__(256) void cvt_hs(const float* __restrict__ hs,
                                              half_t* __restrict__ hsh) {
    int i = (blockIdx.x * 256 + threadIdx.x) * 8;
    f32x4 a = *(const f32x4*)&hs[i];
    f32x4 b = *(const f32x4*)&hs[i + 4];
    half8 o;
    #pragma unroll
    for (int j = 0; j < 4; ++j) { o[j] = (half_t)a[j]; o[4 + j] = (half_t)b[j]; }
    *(half8*)&hsh[i] = o;
}

// ---------------------------------------------------------------------------
// MFMA NT GEMM (m97 structure): C[M,N] = A[M,K]*B[N,K]^T, A/B fp16.
// 128x128 tile, 4 waves 64x64, BK=32, global_load_lds(16B) staging into
// unpadded [128][32] LDS with XOR-swizzled k-chunks.
// ---------------------------------------------------------------------------
__global__ __launch_bounds__(256) void gemm_nt_mfma(const half_t* __restrict__ A,
                                                    const half_t* __restrict__ B,
                                                    void* __restrict__ Cptr,
                                                    int M, int N, int K, int store_half) {
    __shared__ __attribute__((aligned(16))) half_t As[128 * 32];
    __shared__ __attribute__((aligned(16))) half_t Bs[128 * 32];
    int tid = threadIdx.x;
    int w = tid >> 6, lane = tid & 63;
    int c = lane & 15, quad = lane >> 4;
    int rowBase = blockIdx.y * 128, colBase = blockIdx.x * 128;
    int wr = (w & 1) * 64, wc = (w >> 1) * 64;

    f32x4 acc[4][4];
    #pragma unroll
    for (int i = 0; i < 4; ++i)
        #pragma unroll
        for (int j = 0; j < 4; ++j) acc[i][j] = (f32x4)(0.f);

    int srow = tid >> 2;                          // 0..63
    int kcs = ((tid & 3) ^ (srow & 3)) * 8;       // swizzled source k-chunk
    int xk = (quad ^ (c & 3)) * 8;                // frag-read chunk

    for (int k0 = 0; k0 < K; k0 += 32) {
        __syncthreads();                          // readers done with LDS
        gload16(&A[(size_t)(rowBase + srow) * K + k0 + kcs],      &As[w * 512]);
        gload16(&A[(size_t)(rowBase + srow + 64) * K + k0 + kcs], &As[2048 + w * 512]);
        gload16(&B[(size_t)(colBase + srow) * K + k0 + kcs],      &Bs[w * 512]);
        gload16(&B[(size_t)(colBase + srow + 64) * K + k0 + kcs], &Bs[2048 + w * 512]);
        __syncthreads();                          // vmcnt(0) drain

        half8 af[4], bf[4];
        #pragma unroll
        for (int i = 0; i < 4; ++i)
            af[i] = *(const half8*)&As[(wr + i * 16 + c) * 32 + xk];
        #pragma unroll
        for (int j = 0; j < 4; ++j)
            bf[j] = *(const half8*)&Bs[(wc + j * 16 + c) * 32 + xk];
        #pragma unroll
        for (int i = 0; i < 4; ++i)
            #pragma unroll
            for (int j = 0; j < 4; ++j)
                acc[i][j] = __builtin_amdgcn_mfma_f32_16x16x32_f16(af[i], bf[j], acc[i][j], 0, 0, 0);
    }

    #pragma unroll
    for (int i = 0; i < 4; ++i)
        #pragma unroll
        for (int j = 0; j < 4; ++j)
            #pragma unroll
            for (int reg = 0; reg < 4; ++reg) {
                size_t row = rowBase + wr + i * 16 + quad * 4 + reg;
                size_t col = colBase + wc + j * 16 + c;
                if (store_half) ((half_t*)Cptr)[row * N + col] = (half_t)acc[i][j][reg];
                else            ((float*)Cptr)[row * N + col] = acc[i][j][reg];
            }
}

// ---------------------------------------------------------------------------
// transpose V: vt[(b*4+h)*64 + d][n] = qkv[b*2048+n][512 + h*64 + d]
// ---------------------------------------------------------------------------
__global__ __launch_bounds__(256) void transpose_v(const half_t* __restrict__ qkv,
                                                   half_t* __restrict__ vt) {
    __shared__ __attribute__((aligned(16))) half_t T[64 * 65];
    int tid = threadIdx.x;
    int bh = blockIdx.y;
    int b = bh >> 2, h = bh & 3;
    int n0 = blockIdx.x * 64;

    int n = tid >> 2;
    int dc = (tid & 3) * 16;
    const half_t* src = qkv + (size_t)(b * 2048 + n0 + n) * 768 + 512 + h * 64 + dc;
    half8 v0 = *(const half8*)(src);
    half8 v1 = *(const half8*)(src + 8);
    #pragma unroll
    for (int j = 0; j < 8; ++j) {
        T[(dc + j) * 65 + n] = v0[j];
        T[(dc + 8 + j) * 65 + n] = v1[j];
    }
    __syncthreads();

    int d = tid >> 2;
    int nc = (tid & 3) * 16;
    half8 o0, o1;
    #pragma unroll
    for (int j = 0; j < 8; ++j) {
        o0[j] = T[d * 65 + nc + j];
        o1[j] = T[d * 65 + nc + 8 + j];
    }
    half_t* dst = vt + (size_t)(bh * 64 + d) * 2048 + n0 + nc;
    *(half8*)(dst) = o0;
    *(half8*)(dst + 8) = o1;
}

// ---------------------------------------------------------------------------
// Pipelined MFMA flash attention. Block = (b,h) x 64 q-rows, 4 waves x 16.
// K/V staged by async global_load_lds into double-buffered swizzled LDS;
// exactly ONE __syncthreads per K-iter (its vmcnt(0) is the prefetch drain).
// Bias: per-block static window in LDS (log2-domain, pre-scaled).
// P round-trip: wave-private LDS + s_waitcnt lgkmcnt(0) (no block barrier).
// ---------------------------------------------------------------------------
__global__ __launch_bounds__(256) void attn(const half_t* __restrict__ qkv,
                                            const half_t* __restrict__ vt,
                                            const float* __restrict__ btab,
                                            half_t* __restrict__ ab) {
    __shared__ __attribute__((aligned(16))) half_t Ks[2][64 * 64];
    __shared__ __attribute__((aligned(16))) half_t Vts[2][64 * 64];
    __shared__ __attribute__((aligned(16))) half_t Ps[4 * 16 * 72];
    __shared__ float bstat[2112];

    int tid = threadIdx.x;
    int w = tid >> 6, lane = tid & 63;
    int c = lane & 15, quad = lane >> 4;
    int b = blockIdx.z, h = blockIdx.y;
    int q0 = blockIdx.x * 64;
    int bh = b * 4 + h;

    // Q fragments straight from global (A-layout: m=c, k=quad*8+j)
    const half_t* qrow = qkv + (size_t)(b * 2048 + q0 + w * 16 + c) * 768 + h * 64;
    half8 qf0 = *(const half8*)(qrow + quad * 8);
    half8 qf1 = *(const half8*)(qrow + 32 + quad * 8);

    // static bias window: bstat[j] = btab[h*4096 + (2048-q0-63) + j]
    int bbase = h * 4096 + 2048 - q0 - 63;
    for (int j = tid; j < 2112; j += 256) {
        int gi = bbase + j;
        gi = gi > 16383 ? 16383 : gi;
        bstat[j] = btab[gi];
    }

    // staging geometry: slot tid -> row=tid>>3 (0..31; +32 for 2nd instr),
    // lds chunk=tid&7, source chunk xor-swizzled by row&7.
    int srow = tid >> 3;
    int kcs = ((tid & 7) ^ (srow & 7)) * 8;
    const half_t* gK = qkv + (size_t)(b * 2048 + srow) * 768 + 256 + h * 64 + kcs;
    const half_t* gV = vt + (size_t)(bh * 64 + srow) * 2048 + kcs;

    // prologue: tile 0 -> buffer 0
    gload16(gK,             &Ks[0][w * 512]);
    gload16(gK + 32 * 768,  &Ks[0][2048 + w * 512]);
    gload16(gV,             &Vts[0][w * 512]);
    gload16(gV + 32 * 2048, &Vts[0][2048 + w * 512]);
    __syncthreads();   // drains prologue loads + bias staging

    f32x4 O[4];
    #pragma unroll
    for (int i = 0; i < 4; ++i) O[i] = (f32x4)(0.f);
    float mrow[4], lrow[4];
    #pragma unroll
    for (int rg = 0; rg < 4; ++rg) { mrow[rg] = -1e30f; lrow[rg] = 0.f; }

    int rx = c & 7;
    int row0 = w * 16 + quad * 4;
    half_t* pw = &Ps[w * 16 * 72];

    for (int it = 0; it < 32; ++it) {
        int cur = it & 1;
        int ktn = (it + 1) * 64;
        if (ktn < 2048) {                     // async prefetch next tile
            int nxt = cur ^ 1;
            const half_t* gKn = gK + (size_t)ktn * 768;
            const half_t* gVn = gV + ktn;
            gload16(gKn,             &Ks[nxt][w * 512]);
            gload16(gKn + 32 * 768,  &Ks[nxt][2048 + w * 512]);
            gload16(gVn,             &Vts[nxt][w * 512]);
            gload16(gVn + 32 * 2048, &Vts[nxt][2048 + w * 512]);
        }
        int kt = it * 64;
        const half_t* KsC = Ks[cur];
        const half_t* VsC = Vts[cur];

        // S = Q K^T (log2 domain; q pre-scaled)
        f32x4 S[4];
        #pragma unroll
        for (int kb = 0; kb < 4; ++kb) {
            int row = kb * 16 + c;
            half8 b0 = *(const half8*)&KsC[row * 64 + (quad ^ rx) * 8];
            half8 b1 = *(const half8*)&KsC[row * 64 + ((quad + 4) ^ rx) * 8];
            f32x4 a = (f32x4)(0.f);
            a = __builtin_amdgcn_mfma_f32_16x16x32_f16(qf0, b0, a, 0, 0, 0);
            a = __builtin_amdgcn_mfma_f32_16x16x32_f16(qf1, b1, a, 0, 0, 0);
            S[kb] = a;
        }

        // + bias, online max
        float mnew[4];
        #pragma unroll
        for (int rg = 0; rg < 4; ++rg) mnew[rg] = mrow[rg];
        #pragma unroll
        for (int kb = 0; kb < 4; ++kb) {
            int jb = kt + 63 + kb * 16 + c - row0;
            #pragma unroll
            for (int rg = 0; rg < 4; ++rg) {
                float s = S[kb][rg] + bstat[jb - rg];
                S[kb][rg] = s;
                mnew[rg] = fmaxf(mnew[rg], s);
            }
        }
        #pragma unroll
        for (int off = 1; off < 16; off <<= 1)
            #pragma unroll
            for (int rg = 0; rg < 4; ++rg)
                mnew[rg] = fmaxf(mnew[rg], __shfl_xor(mnew[rg], off));

        float alpha[4];
        #pragma unroll
        for (int rg = 0; rg < 4; ++rg) {
            alpha[rg] = exp2f(mrow[rg] - mnew[rg]);
            mrow[rg] = mnew[rg];
        }
        float lsum[4] = {0.f, 0.f, 0.f, 0.f};
        #pragma unroll
        for (int kb = 0; kb < 4; ++kb)
            #pragma unroll
            for (int rg = 0; rg < 4; ++rg) {
                float p = exp2f(S[kb][rg] - mrow[rg]);
                S[kb][rg] = p;
                lsum[rg] += p;
            }
        #pragma unroll
        for (int off = 1; off < 16; off <<= 1)
            #pragma unroll
            for (int rg = 0; rg < 4; ++rg)
                lsum[rg] += __shfl_xor(lsum[rg], off);
        #pragma unroll
        for (int rg = 0; rg < 4; ++rg) lrow[rg] = lrow[rg] * alpha[rg] + lsum[rg];

        // P: C-layout -> wave-private LDS -> A-layout (in-order per wave)
        #pragma unroll
        for (int kb = 0; kb < 4; ++kb)
            #pragma unroll
            for (int rg = 0; rg < 4; ++rg)
                pw[(quad * 4 + rg) * 72 + kb * 16 + c] = (half_t)S[kb][rg];
        __asm__ __volatile__("s_waitcnt lgkmcnt(0)" ::: "memory");

        half8 pf0 = *(const half8*)&pw[c * 72 + quad * 8];
        half8 pf1 = *(const half8*)&pw[c * 72 + 32 + quad * 8];
        #pragma unroll
        for (int db = 0; db < 4; ++db) {
            int row = db * 16 + c;
            f32x4 o = O[db];
            #pragma unroll
            for (int rg = 0; rg < 4; ++rg) o[rg] *= alpha[rg];
            half8 v0 = *(const half8*)&VsC[row * 64 + (quad ^ rx) * 8];
            half8 v1 = *(const half8*)&VsC[row * 64 + ((quad + 4) ^ rx) * 8];
            o = __builtin_amdgcn_mfma_f32_16x16x32_f16(pf0, v0, o, 0, 0, 0);
            o = __builtin_amdgcn_mfma_f32_16x16x32_f16(pf1, v1, o, 0, 0, 0);
            O[db] = o;
        }

        __syncthreads();   // single drain: prefetch done + all waves off cur
    }

    #pragma unroll
    for (int db = 0; db < 4; ++db)
        #pragma unroll
        for (int rg = 0; rg < 4; ++rg) {
            float val = O[db][rg] / lrow[rg];
            ab[(size_t)(b * 2048 + q0 + w * 16 + quad * 4 + rg) * 256
               + h * 64 + db * 16 + c] = (half_t)val;
        }
}

// ---------------------------------------------------------------------------
// Launch. ws (bytes): Wqkv 1.5M | Wo_e .5M | btab 64K | hsh 16M (reused as ab)
//                     | qkv 12M | vt 4M   -> ~34.1 MB
// ---------------------------------------------------------------------------
extern "C" void kernel_launch(void* const* d_in, const int* in_sizes, int n_in,
                              void* d_out, int out_size, void* d_ws, size_t ws_size,
                              hipStream_t stream) {
    (void)in_sizes; (void)n_in; (void)out_size; (void)ws_size;
    const float* hs = (const float*)d_in[0];
    const float* Wq = (const float*)d_in[1];
    const float* Wk = (const float*)d_in[2];
    const float* Wv = (const float*)d_in[3];
    const float* Wo = (const float*)d_in[4];
    const float* rb = (const float*)d_in[5];

    char* p = (char*)d_ws;
    half_t* Wqkv = (half_t*)p;            p += 768 * 1024 * 2;
    half_t* Wo_e = (half_t*)p;            p += 1024 * 256 * 2;
    float*  btab = (float*)p;             p += 4 * 4096 * 4;
    half_t* hsh  = (half_t*)p;            p += (size_t)8192 * 1024 * 2;
    half_t* qkv  = (half_t*)p;            p += (size_t)8192 * 768 * 2;
    half_t* vt   = (half_t*)p;            p += (size_t)16 * 64 * 2048 * 2;
    half_t* ab   = hsh;                   // hsh is dead after the QKV GEMM
    float*  out  = (float*)d_out;

    prep<<<3072, 256, 0, stream>>>(Wq, Wk, Wv, Wo, rb, Wqkv, Wo_e, btab);
    cvt_hs<<<4096, 256, 0, stream>>>(hs, hsh);

    // qkv[8192,768] = hsh[8192,1024] * Wqkv[768,1024]^T
    gemm_nt_mfma<<<dim3(6, 64), 256, 0, stream>>>(hsh, Wqkv, qkv, 8192, 768, 1024, 1);

    transpose_v<<<dim3(32, 16), 256, 0, stream>>>(qkv, vt);

    attn<<<dim3(32, 4, 4), 256, 0, stream>>>(qkv, vt, btab, ab);

    // out[8192,1024] = ab[8192,256] * Wo_e[1024,256]^T
    gemm_nt_mfma<<<dim3(8, 64), 256, 0, stream>>>(ab, Wo_e, out, 8192, 1024, 256, 0);
}

// Round 6
// 193.532 us; speedup vs baseline: 10.4203x; 1.1689x over previous
//
#include <hip/hip_runtime.h>
#include <math.h>

typedef _Float16 half_t;
typedef _Float16 half4 __attribute__((ext_vector_type(4)));
typedef _Float16 half8 __attribute__((ext_vector_type(8)));
typedef float f32x4 __attribute__((ext_vector_type(4)));

#define LOG2E 1.44269504088896f

// async global -> LDS, 16 B per lane; lds base wave-uniform, lane i at base+i*16.
__device__ __forceinline__ void gload16(const void* g, void* l) {
    __builtin_amdgcn_global_load_lds(
        (const __attribute__((address_space(1))) unsigned int*)g,
        (__attribute__((address_space(3))) unsigned int*)l, 16, 0, 0);
}

// ---------------------------------------------------------------------------
// prep: group-reduced effective weights (fp16) + log2-domain bias table (fp32).
// ---------------------------------------------------------------------------
__global__ void prep(const float* __restrict__ Wq, const float* __restrict__ Wk,
                     const float* __restrict__ Wv, const float* __restrict__ Wo,
                     const float* __restrict__ rb,
                     half_t* __restrict__ Wqkv, half_t* __restrict__ Wo_e,
                     float* __restrict__ btab) {
    int idx = blockIdx.x * 256 + threadIdx.x;
    if (idx < 768 * 1024) {
        int row = idx >> 10, col = idx & 1023;
        int sec = row >> 8;
        int r = row & 255;
        int h = r >> 6, d = r & 63;
        const float* W = (sec == 0) ? Wq : ((sec == 1) ? Wk : Wv);
        float s = 0.f;
        #pragma unroll
        for (int g = 0; g < 4; ++g) s += W[((g * 4 + h) * 64 + d) * 1024 + col];
        s *= (sec == 0) ? LOG2E : 0.25f;   // fold log2e into q-projection
        Wqkv[idx] = (half_t)s;
    }
    if (idx < 1024 * 256) {
        int m = idx >> 8, c = idx & 255;
        float s = 0.f;
        #pragma unroll
        for (int g = 0; g < 4; ++g) s += Wo[m * 1024 + g * 256 + c];
        Wo_e[idx] = (half_t)s;
    }
    if (idx < 4 * 4096) {
        int h = idx >> 12, dpos = idx & 4095;
        int delta = dpos - 2048;
        int bucket = (delta > 0) ? 16 : 0;
        int ad = delta < 0 ? -delta : delta;
        if (ad < 8) bucket += ad;
        else {
            int large = 8 + (int)(logf((float)ad * 0.125f) / logf(16.0f) * 8.0f);
            bucket += (large < 15) ? large : 15;
        }
        float s = 0.f;
        #pragma unroll
        for (int g = 0; g < 4; ++g) s += rb[bucket * 16 + g * 4 + h];
        btab[idx] = s * 0.25f * LOG2E;     // log2-domain bias
    }
}

// ---------------------------------------------------------------------------
// hs fp32 -> fp16
// ---------------------------------------------------------------------------
__global__ __launch_bounds__(256) void cvt_hs(const float* __restrict__ hs,
                                              half_t* __restrict__ hsh) {
    int i = (blockIdx.x * 256 + threadIdx.x) * 8;
    f32x4 a = *(const f32x4*)&hs[i];
    f32x4 b = *(const f32x4*)&hs[i + 4];
    half8 o;
    #pragma unroll
    for (int j = 0; j < 4; ++j) { o[j] = (half_t)a[j]; o[4 + j] = (half_t)b[j]; }
    *(half8*)&hsh[i] = o;
}

// ---------------------------------------------------------------------------
// MFMA NT GEMM: C[M,N] = A[M,K]*B[N,K]^T, fp16 in. 128x64 tile (more blocks
// than 128x128 -> 3-4 blocks/CU for our skinny shapes), 4 waves of 64x32,
// BK=32, global_load_lds(16B), XOR-swizzled unpadded LDS.
// ---------------------------------------------------------------------------
__global__ __launch_bounds__(256) void gemm_nt_mfma(const half_t* __restrict__ A,
                                                    const half_t* __restrict__ B,
                                                    void* __restrict__ Cptr,
                                                    int M, int N, int K, int store_half) {
    __shared__ __attribute__((aligned(16))) half_t As[128 * 32];
    __shared__ __attribute__((aligned(16))) half_t Bs[64 * 32];
    int tid = threadIdx.x;
    int w = tid >> 6, lane = tid & 63;
    int c = lane & 15, quad = lane >> 4;
    int rowBase = blockIdx.y * 128, colBase = blockIdx.x * 64;
    int wr = (w & 1) * 64, wc = (w >> 1) * 32;

    f32x4 acc[4][2];
    #pragma unroll
    for (int i = 0; i < 4; ++i)
        #pragma unroll
        for (int j = 0; j < 2; ++j) acc[i][j] = (f32x4)(0.f);

    int srow = tid >> 2;                          // 0..63
    int kcs = ((tid & 3) ^ (srow & 3)) * 8;       // swizzled source k-chunk
    int xk = (quad ^ (c & 3)) * 8;                // frag-read chunk

    for (int k0 = 0; k0 < K; k0 += 32) {
        __syncthreads();
        gload16(&A[(size_t)(rowBase + srow) * K + k0 + kcs],      &As[w * 512]);
        gload16(&A[(size_t)(rowBase + srow + 64) * K + k0 + kcs], &As[2048 + w * 512]);
        gload16(&B[(size_t)(colBase + srow) * K + k0 + kcs],      &Bs[w * 512]);
        __syncthreads();

        half8 af[4], bf[2];
        #pragma unroll
        for (int i = 0; i < 4; ++i)
            af[i] = *(const half8*)&As[(wr + i * 16 + c) * 32 + xk];
        #pragma unroll
        for (int j = 0; j < 2; ++j)
            bf[j] = *(const half8*)&Bs[(wc + j * 16 + c) * 32 + xk];
        #pragma unroll
        for (int i = 0; i < 4; ++i)
            #pragma unroll
            for (int j = 0; j < 2; ++j)
                acc[i][j] = __builtin_amdgcn_mfma_f32_16x16x32_f16(af[i], bf[j], acc[i][j], 0, 0, 0);
    }

    #pragma unroll
    for (int i = 0; i < 4; ++i)
        #pragma unroll
        for (int j = 0; j < 2; ++j)
            #pragma unroll
            for (int reg = 0; reg < 4; ++reg) {
                size_t row = rowBase + wr + i * 16 + quad * 4 + reg;
                size_t col = colBase + wc + j * 16 + c;
                if (store_half) ((half_t*)Cptr)[row * N + col] = (half_t)acc[i][j][reg];
                else            ((float*)Cptr)[row * N + col] = acc[i][j][reg];
            }
}

// ---------------------------------------------------------------------------
// transpose V: vt[(b*4+h)*64 + d][n] = qkv[b*2048+n][512 + h*64 + d]
// ---------------------------------------------------------------------------
__global__ __launch_bounds__(256) void transpose_v(const half_t* __restrict__ qkv,
                                                   half_t* __restrict__ vt) {
    __shared__ __attribute__((aligned(16))) half_t T[64 * 65];
    int tid = threadIdx.x;
    int bh = blockIdx.y;
    int b = bh >> 2, h = bh & 3;
    int n0 = blockIdx.x * 64;

    int n = tid >> 2;
    int dc = (tid & 3) * 16;
    const half_t* src = qkv + (size_t)(b * 2048 + n0 + n) * 768 + 512 + h * 64 + dc;
    half8 v0 = *(const half8*)(src);
    half8 v1 = *(const half8*)(src + 8);
    #pragma unroll
    for (int j = 0; j < 8; ++j) {
        T[(dc + j) * 65 + n] = v0[j];
        T[(dc + 8 + j) * 65 + n] = v1[j];
    }
    __syncthreads();

    int d = tid >> 2;
    int nc = (tid & 3) * 16;
    half8 o0, o1;
    #pragma unroll
    for (int j = 0; j < 8; ++j) {
        o0[j] = T[d * 65 + nc + j];
        o1[j] = T[d * 65 + nc + 8 + j];
    }
    half_t* dst = vt + (size_t)(bh * 64 + d) * 2048 + n0 + nc;
    *(half8*)(dst) = o0;
    *(half8*)(dst + 8) = o1;
}

// ---------------------------------------------------------------------------
// Split-K flash attention, S^T formulation.
// Block = (qtile 64, h, b, split s): keys [s*1024, s*1024+1024), 16 iters.
// S^T = K Q^T via MFMA(A=K-frag, B=Q-frag) -> D[key, q]: each lane owns ONE
// q-row (col c) and 16 keys -> softmax: in-lane reduce + 2 shfl steps.
// Far tiles (|delta|>=128 everywhere) use constant bias folded into m.
// Writes unnormalized partial O (fp16) + m,l (fp32); merged by merge().
// ---------------------------------------------------------------------------
__global__ __launch_bounds__(256) void attn(const half_t* __restrict__ qkv,
                                            const half_t* __restrict__ vt,
                                            const float* __restrict__ btab,
                                            half_t* __restrict__ Opart,
                                            float* __restrict__ ml) {
    __shared__ __attribute__((aligned(16))) half_t Ks[64 * 64];
    __shared__ __attribute__((aligned(16))) half_t Vts[64 * 64];
    __shared__ __attribute__((aligned(16))) half_t Ps[4 * 16 * 72];
    __shared__ float bstat[1152];

    int tid = threadIdx.x;
    int w = tid >> 6, lane = tid & 63;
    int c = lane & 15, quad = lane >> 4;
    int qt = blockIdx.x, h = blockIdx.y;
    int b = blockIdx.z >> 1, s = blockIdx.z & 1;
    int q0 = qt * 64;
    int bh = b * 4 + h;
    int k0g = s * 1024;

    // Q fragments straight from global (B-operand: n=q=c, k=quad*8+j)
    const half_t* qrow = qkv + (size_t)(b * 2048 + q0 + w * 16 + c) * 768 + h * 64;
    half8 qf0 = *(const half8*)(qrow + quad * 8);
    half8 qf1 = *(const half8*)(qrow + 32 + quad * 8);

    // far-field bias constants (bucket saturates for |delta|>=128)
    float cpos = btab[h * 4096 + 4095];
    float cneg = btab[h * 4096];

    // bias window: bstat[j] = btab[h][clamp(k0g - q0 - 63 + 2048 + j)]
    int bbase = k0g - q0 - 63 + 2048;
    for (int j = tid; j < 1152; j += 256) {
        int gi = bbase + j;
        gi = gi < 0 ? 0 : (gi > 4095 ? 4095 : gi);
        bstat[j] = btab[h * 4096 + gi];
    }

    // staging geometry: srow = tid>>3 (0..31, +32 on 2nd instr), chunk tid&7,
    // source chunk xor-swizzled by row&7.
    int srow = tid >> 3;
    int kcs = ((tid & 7) ^ (srow & 7)) * 8;
    const half_t* gK = qkv + (size_t)(b * 2048 + k0g + srow) * 768 + 256 + h * 64 + kcs;
    const half_t* gV = vt + (size_t)(bh * 64 + srow) * 2048 + k0g + kcs;

    f32x4 O[4];
    #pragma unroll
    for (int i = 0; i < 4; ++i) O[i] = (f32x4)(0.f);
    float mrow = -1e30f, lrow = 0.f;

    int rx = c & 7;
    half_t* pw = &Ps[w * 16 * 72];

    for (int it = 0; it < 16; ++it) {
        int ktg = k0g + it * 64;                  // global tile start
        __syncthreads();                          // all waves done with LDS
        {
            const half_t* gKt = gK + (size_t)(it * 64) * 768;
            const half_t* gVt = gV + it * 64;
            gload16(gKt,                     &Ks[w * 512]);
            gload16(gKt + (size_t)32 * 768,  &Ks[2048 + w * 512]);
            gload16(gVt,                     &Vts[w * 512]);
            gload16(gVt + 32 * 2048,         &Vts[2048 + w * 512]);
        }
        __syncthreads();                          // vmcnt(0) drain

        // S^T = K Q^T : D[key = kb*16 + quad*4+rg, q = w*16 + c]
        f32x4 ST[4];
        #pragma unroll
        for (int kb = 0; kb < 4; ++kb) {
            int row = kb * 16 + c;
            half8 kf0 = *(const half8*)&Ks[row * 64 + (quad ^ rx) * 8];
            half8 kf1 = *(const half8*)&Ks[row * 64 + ((quad + 4) ^ rx) * 8];
            f32x4 a = (f32x4)(0.f);
            a = __builtin_amdgcn_mfma_f32_16x16x32_f16(kf0, qf0, a, 0, 0, 0);
            a = __builtin_amdgcn_mfma_f32_16x16x32_f16(kf1, qf1, a, 0, 0, 0);
            ST[kb] = a;
        }

        // bias: constant fast path for far tiles, LDS path for near
        float cb;
        if (ktg >= q0 + 191) {
            cb = cpos;
        } else if (ktg + 191 <= q0) {
            cb = cneg;
        } else {
            cb = 0.f;
            int jb = it * 64 + 63 - (w * 16 + c);
            #pragma unroll
            for (int kb = 0; kb < 4; ++kb)
                #pragma unroll
                for (int rg = 0; rg < 4; ++rg)
                    ST[kb][rg] += bstat[jb + kb * 16 + quad * 4 + rg];
        }

        // row max: in-lane 16 -> cross-quad (2 shfl)
        float tmax = -1e30f;
        #pragma unroll
        for (int kb = 0; kb < 4; ++kb)
            #pragma unroll
            for (int rg = 0; rg < 4; ++rg) tmax = fmaxf(tmax, ST[kb][rg]);
        tmax += cb;
        tmax = fmaxf(tmax, __shfl_xor(tmax, 16));
        tmax = fmaxf(tmax, __shfl_xor(tmax, 32));

        float mnew = fmaxf(mrow, tmax);
        float alpha = exp2f(mrow - mnew);
        mrow = mnew;
        float madj = mnew - cb;

        // p = exp2(S - madj); pack 4 contiguous keys -> ds_write_b64
        float lsum = 0.f;
        #pragma unroll
        for (int kb = 0; kb < 4; ++kb) {
            half4 pk;
            #pragma unroll
            for (int rg = 0; rg < 4; ++rg) {
                float p = exp2f(ST[kb][rg] - madj);
                lsum += p;
                pk[rg] = (half_t)p;
            }
            *(half4*)&pw[c * 72 + kb * 16 + quad * 4] = pk;
        }
        lsum += __shfl_xor(lsum, 16);
        lsum += __shfl_xor(lsum, 32);
        lrow = lrow * alpha + lsum;

        __asm__ __volatile__("s_waitcnt lgkmcnt(0)" ::: "memory");  // wave-private Ps

        // O[q, d] += P V  (A = P[q,key] from Ps, B = Vt[d,key])
        half8 pf0 = *(const half8*)&pw[c * 72 + quad * 8];
        half8 pf1 = *(const half8*)&pw[c * 72 + 32 + quad * 8];
        float alphar[4];
        #pragma unroll
        for (int rg = 0; rg < 4; ++rg) alphar[rg] = __shfl(alpha, quad * 4 + rg);
        #pragma unroll
        for (int db = 0; db < 4; ++db) {
            int row = db * 16 + c;
            f32x4 o = O[db];
            #pragma unroll
            for (int rg = 0; rg < 4; ++rg) o[rg] *= alphar[rg];
            half8 v0 = *(const half8*)&Vts[row * 64 + (quad ^ rx) * 8];
            half8 v1 = *(const half8*)&Vts[row * 64 + ((quad + 4) ^ rx) * 8];
            o = __builtin_amdgcn_mfma_f32_16x16x32_f16(pf0, v0, o, 0, 0, 0);
            o = __builtin_amdgcn_mfma_f32_16x16x32_f16(pf1, v1, o, 0, 0, 0);
            O[db] = o;
        }
    }

    // store unnormalized partial (O rows = q = w*16 + quad*4+rg, cols = d)
    int pb = (bh * 32 + qt) * 2 + s;
    #pragma unroll
    for (int db = 0; db < 4; ++db)
        #pragma unroll
        for (int rg = 0; rg < 4; ++rg)
            Opart[((size_t)pb * 64 + w * 16 + quad * 4 + rg) * 64 + db * 16 + c] =
                (half_t)O[db][rg];
    if (quad == 0) {
        ml[pb * 128 + w * 16 + c] = mrow;
        ml[pb * 128 + 64 + w * 16 + c] = lrow;
    }
}

// ---------------------------------------------------------------------------
// merge the two split-K partials -> ab[b*2048+n][h*64+d]
// ---------------------------------------------------------------------------
__global__ __launch_bounds__(256) void merge(const half_t* __restrict__ Opart,
                                             const float* __restrict__ ml,
                                             half_t* __restrict__ ab) {
    int bq = blockIdx.x;            // bh*32 + qt
    int bh = bq >> 5, qt = bq & 31;
    int b = bh >> 2, h = bh & 3;
    int row = threadIdx.x >> 2;
    int cg = (threadIdx.x & 3) * 16;
    int p0 = bq * 2, p1 = p0 + 1;
    float m1 = ml[p0 * 128 + row], l1 = ml[p0 * 128 + 64 + row];
    float m2 = ml[p1 * 128 + row], l2 = ml[p1 * 128 + 64 + row];
    float m = fmaxf(m1, m2);
    float w1 = exp2f(m1 - m), w2 = exp2f(m2 - m);
    float inv = 1.f / (l1 * w1 + l2 * w2);
    const half8* o1 = (const half8*)&Opart[((size_t)p0 * 64 + row) * 64 + cg];
    const half8* o2 = (const half8*)&Opart[((size_t)p1 * 64 + row) * 64 + cg];
    half_t* dst = ab + (size_t)(b * 2048 + qt * 64 + row) * 256 + h * 64 + cg;
    #pragma unroll
    for (int v = 0; v < 2; ++v) {
        half8 x = o1[v], y = o2[v], o;
        #pragma unroll
        for (int j = 0; j < 8; ++j)
            o[j] = (half_t)(((float)x[j] * w1 + (float)y[j] * w2) * inv);
        *(half8*)(dst + v * 8) = o;
    }
}

// ---------------------------------------------------------------------------
// Launch. ws: Wqkv 1.5M | Wo_e .5M | btab 64K | hsh 16M | qkv 12M | vt 4M
// hsh region reused after QKV GEMM: Opart (8.4M) @0, ml (.5M) @8.4M, ab (4M) @9M
// ---------------------------------------------------------------------------
extern "C" void kernel_launch(void* const* d_in, const int* in_sizes, int n_in,
                              void* d_out, int out_size, void* d_ws, size_t ws_size,
                              hipStream_t stream) {
    (void)in_sizes; (void)n_in; (void)out_size; (void)ws_size;
    const float* hs = (const float*)d_in[0];
    const float* Wq = (const float*)d_in[1];
    const float* Wk = (const float*)d_in[2];
    const float* Wv = (const float*)d_in[3];
    const float* Wo = (const float*)d_in[4];
    const float* rb = (const float*)d_in[5];

    char* p = (char*)d_ws;
    half_t* Wqkv = (half_t*)p;            p += 768 * 1024 * 2;
    half_t* Wo_e = (half_t*)p;            p += 1024 * 256 * 2;
    float*  btab = (float*)p;             p += 4 * 4096 * 4;
    char*   hshp = p;                     p += (size_t)8192 * 1024 * 2;
    half_t* qkv  = (half_t*)p;            p += (size_t)8192 * 768 * 2;
    half_t* vt   = (half_t*)p;            p += (size_t)16 * 64 * 2048 * 2;
    half_t* hsh   = (half_t*)hshp;
    half_t* Opart = (half_t*)hshp;                               // 8.4 MB
    float*  mlbuf = (float*)(hshp + (size_t)1024 * 64 * 64 * 2); // 0.5 MB
    half_t* ab    = (half_t*)(hshp + (size_t)9 * 1024 * 1024);   // 4 MB
    float*  out  = (float*)d_out;

    prep<<<3072, 256, 0, stream>>>(Wq, Wk, Wv, Wo, rb, Wqkv, Wo_e, btab);
    cvt_hs<<<4096, 256, 0, stream>>>(hs, hsh);

    // qkv[8192,768] = hsh[8192,1024] * Wqkv[768,1024]^T   (768 blocks, 3/CU)
    gemm_nt_mfma<<<dim3(12, 64), 256, 0, stream>>>(hsh, Wqkv, qkv, 8192, 768, 1024, 1);

    transpose_v<<<dim3(32, 16), 256, 0, stream>>>(qkv, vt);

    // split-K=2 flash attention (1024 blocks, 4/CU)
    attn<<<dim3(32, 4, 8), 256, 0, stream>>>(qkv, vt, btab, Opart, mlbuf);
    merge<<<512, 256, 0, stream>>>(Opart, mlbuf, ab);

    // out[8192,1024] = ab[8192,256] * Wo_e[1024,256]^T   (1024 blocks, 4/CU)
    gemm_nt_mfma<<<dim3(16, 64), 256, 0, stream>>>(ab, Wo_e, out, 8192, 1024, 256, 0);
}